// Round 8
// baseline (830.875 us; speedup 1.0000x reference)
//
#include <hip/hip_runtime.h>

// SIREN INR MLP — numpy-float32 emulation, packed-fp32.
// R7 (PASS, 443us): L0/L1 numpy-exact tree, L2/L3 fma-chain dots, rintf sin.
// R8 (bit-exact deltas only):
//  (a) q-bit extraction via EXACT add: qf is an integer float from rintf;
//      mg = qf + 1.5*2^23 is exact (both integers, sum < 2^24) -> mantissa low
//      bits = q mod 4. Removes v_cvt_i32_f32 (2/sin) and the sign-select
//      compare chain; sign applied by xor of ((bits&2)<<30).
//      (R6's failed magic trick rounded t+MAGIC to *produce* qf; here qf still
//       comes from rintf — extraction add has zero rounding.)
//  (b) __launch_bounds__(256, 8): request 8 waves/SIMD residency (VGPR 52 fits).
//  (c) packed final clamp.

typedef float v2f __attribute__((ext_vector_type(2)));

static constexpr int PW = 921;
static constexpr float MAGIC = 12582912.0f;   // 1.5 * 2^23

__device__ __forceinline__ v2f fma2(v2f a, v2f b, v2f c) {
    return __builtin_elementwise_fma(a, b, c);
}
__device__ __forceinline__ v2f splat2(float x) { v2f r; r.x = x; r.y = x; return r; }

// numpy SIMD f32 sin, 2 points packed. qf from rintf (R4/R7-proven);
// quadrant bits from exact magic-add on qf; select/sign via bit ops.
__device__ __forceinline__ v2f np_sinf2(v2f x) {
#pragma clang fp contract(off)
    v2f t = x * splat2(0x1.45f306p-1f);
    v2f qf; qf.x = __builtin_rintf(t.x); qf.y = __builtin_rintf(t.y);
    // exact: qf integer, |qf| < 300, so qf + 1.5*2^23 is exactly representable
    const unsigned mx = __builtin_bit_cast(unsigned, __fadd_rn(qf.x, MAGIC));
    const unsigned my = __builtin_bit_cast(unsigned, __fadd_rn(qf.y, MAGIC));
    v2f r = fma2(qf, splat2(-0x1.921fb0p+0f), x);
    r = fma2(qf, splat2(-0x1.5110b4p-22f), r);
    r = fma2(qf, splat2(-0x1.846988p-48f), r);
    v2f r2 = r * r;
    v2f ys = fma2(splat2(0x1.5e9e9cp-19f), r2, splat2(-0x1.a06bbap-13f));
    ys = fma2(ys, r2, splat2(0x1.11119ap-7f));
    ys = fma2(ys, r2, splat2(-0x1.555556p-3f));
    ys = ys * r2;
    ys = fma2(ys, r, r);
    v2f yc = fma2(splat2(0x1.98e616p-16f), r2, splat2(-0x1.6c06dcp-10f));
    yc = fma2(yc, r2, splat2(0x1.55553cp-5f));
    yc = fma2(yc, r2, splat2(-0.5f));
    yc = fma2(yc, r2, splat2(1.0f));
    float rx = (mx & 1u) ? yc.x : ys.x;
    float ry = (my & 1u) ? yc.y : ys.y;
    const unsigned sx = (mx & 2u) << 30;   // q&2 -> sign bit
    const unsigned sy = (my & 2u) << 30;
    v2f res;
    res.x = __builtin_bit_cast(float, __builtin_bit_cast(unsigned, rx) ^ sx);
    res.y = __builtin_bit_cast(float, __builtin_bit_cast(unsigned, ry) ^ sy);
    return res;
}

// numpy einsum contig_contig_outstride0_two tree (exact) — L1.
__device__ __forceinline__ v2f np_dot20_2(const float* __restrict__ w,
                                          const v2f* h) {
#pragma clang fp contract(off)
    v2f s[4];
#pragma unroll
    for (int j = 0; j < 4; ++j) {
        v2f p0  = h[j]      * splat2(w[j]);
        v2f p4  = h[4 + j]  * splat2(w[4 + j]);
        v2f p8  = h[8 + j]  * splat2(w[8 + j]);
        v2f p12 = h[12 + j] * splat2(w[12 + j]);
        v2f p16 = h[16 + j] * splat2(w[16 + j]);
        v2f t = p8 + p12;
        t = p4 + t;
        t = p0 + t;
        s[j] = p16 + t;
    }
    return (s[0] + s[1]) + (s[2] + s[3]);
}

// FMA-chain dot (bias-initialized) — L2/L3 only (bounded amplification).
__device__ __forceinline__ v2f fma_dot20(const float* __restrict__ w,
                                         const v2f* h, float bias) {
#pragma clang fp contract(off)
    v2f acc = splat2(bias);
#pragma unroll
    for (int i = 0; i < 20; ++i)
        acc = fma2(splat2(w[i]), h[i], acc);
    return acc;
}

__global__ void __launch_bounds__(256, 8)
siren_mlp(const float* __restrict__ coords,
          const float* __restrict__ weights,
          float* __restrict__ out, int N)
{
#pragma clang fp contract(off)
    const int b = blockIdx.y;
    const float* __restrict__ w = weights + b * PW;  // wave-uniform -> s_load
    const int n0 = blockIdx.x * 512 + threadIdx.x;
    const int n1 = n0 + 256;
    const size_t base = (size_t)b * N;

    const float2* __restrict__ cp = (const float2*)coords;
    const float2 c0 = cp[base + n0];
    const float2 c1 = cp[base + n1];
    v2f X; X.x = c0.x; X.y = c1.x;
    v2f Y; Y.x = c0.y; Y.y = c1.y;

    v2f h[20], g[20];

    // ---- layer 0: 2 -> 20. (x*w0)+(y*w1), +b, *20 — numpy-exact, no fma.
#pragma unroll
    for (int o = 0; o < 20; ++o) {
        v2f z = (X * splat2(w[2 * o])) + (Y * splat2(w[2 * o + 1]));
        z = z + splat2(w[40 + o]);
        h[o] = np_sinf2(splat2(20.0f) * z);
    }

    // ---- layer 1: 20 -> 20 — numpy-exact tree.
#pragma unroll
    for (int o = 0; o < 20; ++o) {
        v2f z = np_dot20_2(w + 60 + 20 * o, h) + splat2(w[460 + o]);
        g[o] = np_sinf2(splat2(20.0f) * z);
    }

    // ---- layer 2: 20 -> 20 — fma chain.
#pragma unroll
    for (int o = 0; o < 20; ++o) {
        v2f z = fma_dot20(w + 480 + 20 * o, g, w[880 + o]);
        h[o] = np_sinf2(splat2(20.0f) * z);
    }

    // ---- layer 3: 20 -> 1, clip[0,1] — fma chain, packed clamp.
    {
        v2f z = fma_dot20(w + 900, h, w[920]);
        z = __builtin_elementwise_max(z, splat2(0.0f));
        z = __builtin_elementwise_min(z, splat2(1.0f));
        out[base + n0] = z.x;
        out[base + n1] = z.y;
    }
}

extern "C" void kernel_launch(void* const* d_in, const int* in_sizes, int n_in,
                              void* d_out, int out_size, void* d_ws, size_t ws_size,
                              hipStream_t stream) {
    const float* coords  = (const float*)d_in[0];
    const float* weights = (const float*)d_in[1];
    float* out = (float*)d_out;

    const int B = in_sizes[1] / PW;            // 128
    const int N = in_sizes[0] / (2 * B);       // 65536

    dim3 grid(N / 512, B);
    siren_mlp<<<grid, dim3(256), 0, stream>>>(coords, weights, out, N);
}

// Round 9
// 435.365 us; speedup vs baseline: 1.9085x; 1.9085x over previous
//
#include <hip/hip_runtime.h>

// SIREN INR MLP — numpy-float32 emulation, packed-fp32.
// R7 (PASS 443us): L0/L1 numpy-exact tree, L2/L3 fma-chain, rintf sin.
// R8: +magic-bit quadrant extraction (PROVEN bit-exact: absmax unchanged)
//     +launch_bounds(256,8) -> VGPR capped 32 -> scratch spills, 3.1GB HBM, 830us.
// R9 = R8's sin + R7's launch bounds (VGPR ~52, no spills).
//  sin: qf from rintf; quadrant bits via EXACT add qf+1.5*2^23 (qf integer,
//  sum < 2^24 => no rounding); select on mantissa bit0, sign xor on bit1.
//  Removes v_cvt_i32_f32 x2 + compare chain per sin.

typedef float v2f __attribute__((ext_vector_type(2)));

static constexpr int PW = 921;
static constexpr float MAGIC = 12582912.0f;   // 1.5 * 2^23

__device__ __forceinline__ v2f fma2(v2f a, v2f b, v2f c) {
    return __builtin_elementwise_fma(a, b, c);
}
__device__ __forceinline__ v2f splat2(float x) { v2f r; r.x = x; r.y = x; return r; }

// numpy SIMD f32 sin, 2 points packed (bit-exact config verified in R8).
__device__ __forceinline__ v2f np_sinf2(v2f x) {
#pragma clang fp contract(off)
    v2f t = x * splat2(0x1.45f306p-1f);
    v2f qf; qf.x = __builtin_rintf(t.x); qf.y = __builtin_rintf(t.y);
    const unsigned mx = __builtin_bit_cast(unsigned, __fadd_rn(qf.x, MAGIC));
    const unsigned my = __builtin_bit_cast(unsigned, __fadd_rn(qf.y, MAGIC));
    v2f r = fma2(qf, splat2(-0x1.921fb0p+0f), x);
    r = fma2(qf, splat2(-0x1.5110b4p-22f), r);
    r = fma2(qf, splat2(-0x1.846988p-48f), r);
    v2f r2 = r * r;
    v2f ys = fma2(splat2(0x1.5e9e9cp-19f), r2, splat2(-0x1.a06bbap-13f));
    ys = fma2(ys, r2, splat2(0x1.11119ap-7f));
    ys = fma2(ys, r2, splat2(-0x1.555556p-3f));
    ys = ys * r2;
    ys = fma2(ys, r, r);
    v2f yc = fma2(splat2(0x1.98e616p-16f), r2, splat2(-0x1.6c06dcp-10f));
    yc = fma2(yc, r2, splat2(0x1.55553cp-5f));
    yc = fma2(yc, r2, splat2(-0.5f));
    yc = fma2(yc, r2, splat2(1.0f));
    float rx = (mx & 1u) ? yc.x : ys.x;
    float ry = (my & 1u) ? yc.y : ys.y;
    const unsigned sx = (mx & 2u) << 30;   // q&2 -> sign bit
    const unsigned sy = (my & 2u) << 30;
    v2f res;
    res.x = __builtin_bit_cast(float, __builtin_bit_cast(unsigned, rx) ^ sx);
    res.y = __builtin_bit_cast(float, __builtin_bit_cast(unsigned, ry) ^ sy);
    return res;
}

// numpy einsum contig_contig_outstride0_two tree (exact) — L1.
__device__ __forceinline__ v2f np_dot20_2(const float* __restrict__ w,
                                          const v2f* h) {
#pragma clang fp contract(off)
    v2f s[4];
#pragma unroll
    for (int j = 0; j < 4; ++j) {
        v2f p0  = h[j]      * splat2(w[j]);
        v2f p4  = h[4 + j]  * splat2(w[4 + j]);
        v2f p8  = h[8 + j]  * splat2(w[8 + j]);
        v2f p12 = h[12 + j] * splat2(w[12 + j]);
        v2f p16 = h[16 + j] * splat2(w[16 + j]);
        v2f t = p8 + p12;
        t = p4 + t;
        t = p0 + t;
        s[j] = p16 + t;
    }
    return (s[0] + s[1]) + (s[2] + s[3]);
}

// FMA-chain dot (bias-initialized) — L2/L3 only (bounded amplification).
__device__ __forceinline__ v2f fma_dot20(const float* __restrict__ w,
                                         const v2f* h, float bias) {
#pragma clang fp contract(off)
    v2f acc = splat2(bias);
#pragma unroll
    for (int i = 0; i < 20; ++i)
        acc = fma2(splat2(w[i]), h[i], acc);
    return acc;
}

__global__ void __launch_bounds__(256)
siren_mlp(const float* __restrict__ coords,
          const float* __restrict__ weights,
          float* __restrict__ out, int N)
{
#pragma clang fp contract(off)
    const int b = blockIdx.y;
    const float* __restrict__ w = weights + b * PW;  // wave-uniform -> s_load
    const int n0 = blockIdx.x * 512 + threadIdx.x;
    const int n1 = n0 + 256;
    const size_t base = (size_t)b * N;

    const float2* __restrict__ cp = (const float2*)coords;
    const float2 c0 = cp[base + n0];
    const float2 c1 = cp[base + n1];
    v2f X; X.x = c0.x; X.y = c1.x;
    v2f Y; Y.x = c0.y; Y.y = c1.y;

    v2f h[20], g[20];

    // ---- layer 0: 2 -> 20. (x*w0)+(y*w1), +b, *20 — numpy-exact, no fma.
#pragma unroll
    for (int o = 0; o < 20; ++o) {
        v2f z = (X * splat2(w[2 * o])) + (Y * splat2(w[2 * o + 1]));
        z = z + splat2(w[40 + o]);
        h[o] = np_sinf2(splat2(20.0f) * z);
    }

    // ---- layer 1: 20 -> 20 — numpy-exact tree.
#pragma unroll
    for (int o = 0; o < 20; ++o) {
        v2f z = np_dot20_2(w + 60 + 20 * o, h) + splat2(w[460 + o]);
        g[o] = np_sinf2(splat2(20.0f) * z);
    }

    // ---- layer 2: 20 -> 20 — fma chain.
#pragma unroll
    for (int o = 0; o < 20; ++o) {
        v2f z = fma_dot20(w + 480 + 20 * o, g, w[880 + o]);
        h[o] = np_sinf2(splat2(20.0f) * z);
    }

    // ---- layer 3: 20 -> 1, clip[0,1] — fma chain, packed clamp.
    {
        v2f z = fma_dot20(w + 900, h, w[920]);
        z = __builtin_elementwise_max(z, splat2(0.0f));
        z = __builtin_elementwise_min(z, splat2(1.0f));
        out[base + n0] = z.x;
        out[base + n1] = z.y;
    }
}

extern "C" void kernel_launch(void* const* d_in, const int* in_sizes, int n_in,
                              void* d_out, int out_size, void* d_ws, size_t ws_size,
                              hipStream_t stream) {
    const float* coords  = (const float*)d_in[0];
    const float* weights = (const float*)d_in[1];
    float* out = (float*)d_out;

    const int B = in_sizes[1] / PW;            // 128
    const int N = in_sizes[0] / (2 * B);       // 65536

    dim3 grid(N / 512, B);
    siren_mlp<<<grid, dim3(256), 0, stream>>>(coords, weights, out, N);
}